// Round 14
// baseline (72.825 us; speedup 1.0000x reference)
//
#include <hip/hip_runtime.h>
#include <hip/hip_bf16.h>

// CrossAttention: q = x@Wq+bq; k = cond@Wk+bk; v = cond@Wv+bv
// scores = q@k^T (UNSCALED); attn = softmax(scores); out = attn@v
// B=4, Lq=Lk=4096, IN=COND=256, OUT_DIM=128. Output fp32.
//
// r14: attn restructured around __builtin_amdgcn_global_load_lds (T3/T4):
// loads hold ZERO VGPRs in flight (r7-r13: allocator clamped 128 VGPR and
// serialized register prefetch), and LDS tiles are shared by 2 q-subtile
// waves (L2 traffic 1GB -> 512MB). Counted vmcnt(8), raw s_barrier.

typedef __attribute__((ext_vector_type(8))) short short8;
typedef __attribute__((ext_vector_type(8))) unsigned short ushort8;
typedef __attribute__((ext_vector_type(4))) unsigned short us4;
typedef __attribute__((ext_vector_type(4))) float f32x4;
typedef __attribute__((ext_vector_type(16))) float f32x16;
typedef __attribute__((ext_vector_type(4))) unsigned int u32x4;
typedef __bf16 bf16x8 __attribute__((ext_vector_type(8)));

constexpr int BATCH  = 4;
constexpr int SEQLEN = 4096;   // Lq == Lk
constexpr int DIN    = 256;
constexpr int DOUT   = 128;
constexpr int ROWS   = BATCH * SEQLEN;  // 16384
constexpr float LOG2E = 1.4426950408889634f;

static __device__ __forceinline__ unsigned short bf16_rn(float f) {
  unsigned int u = __builtin_bit_cast(unsigned int, f);
  unsigned int r = u + 0x7FFFu + ((u >> 16) & 1u);
  return (unsigned short)(r >> 16);
}
static __device__ __forceinline__ float bf16_f32(unsigned short h) {
  return __builtin_bit_cast(float, (unsigned int)h << 16);
}
static __device__ __forceinline__ float exp2n(float x) {
  return __builtin_amdgcn_exp2f(x);    // native v_exp_f32
}

static __device__ __forceinline__ f32x4 mfma_bf16(short8 a, short8 b, f32x4 c) {
  return __builtin_amdgcn_mfma_f32_16x16x32_bf16(
      __builtin_bit_cast(bf16x8, a), __builtin_bit_cast(bf16x8, b), c, 0, 0, 0);
}
static __device__ __forceinline__ f32x16 mfma32(short8 a, short8 b, f32x16 c) {
  return __builtin_amdgcn_mfma_f32_32x32x16_bf16(
      __builtin_bit_cast(bf16x8, a), __builtin_bit_cast(bf16x8, b), c, 0, 0, 0);
}

// D = [bf16(S0) | bf16(S1)<<16]
static __device__ __forceinline__ unsigned int cvt_pk(float lo, float hi) {
  unsigned int r;
  asm("v_cvt_pk_bf16_f32 %0, %1, %2" : "=v"(r) : "v"(lo), "v"(hi));
  return r;
}
// v_permlane32_swap_b32 vdst, vsrc: a.hi32lanes <-> b.lo32lanes
static __device__ __forceinline__ void permswap(unsigned int& a, unsigned int& b) {
  asm("v_permlane32_swap_b32 %0, %1" : "+v"(a), "+v"(b));
}

// async global->LDS, 16B per lane: LDS dest = uniform base + lane*16,
// global src = per-lane pointer (our fragment-major layout matches exactly).
static __device__ __forceinline__ void gl16(const void* g, void* l) {
  __builtin_amdgcn_global_load_lds(
      (const __attribute__((address_space(1))) unsigned int*)g,
      (__attribute__((address_space(3))) unsigned int*)l, 16, 0, 0);
}

static __device__ __forceinline__ int swz128(int a) {
  return a ^ (((a >> 7) & 7) << 4);
}
// K-bounce tile (row stride 256B): fold row bits 0-3 into byte bits 4-7
static __device__ __forceinline__ int swzK(int a) {
  return a ^ (((a >> 8) & 15) << 4);
}

// Fragment-major global layouts (written by proj, read coalesced by attn):
//  K: kfb[b][kblk(128)][f(8)][lane(64)] x 16B
//  V: vfb[b][kblk(128)][dblk(4)][kk(2)][lane(64)] x 16B

// ---------------- projection via MFMA, split-precision --------------------
// out = (A_hi + A_lo) @ W_bf16 + b, f32 accumulate. (r10-verified version)
__global__ __launch_bounds__(256) void proj_kernel(
    const float* __restrict__ x, const float* __restrict__ cond,
    const float* __restrict__ Wq, const float* __restrict__ bq,
    const float* __restrict__ Wk, const float* __restrict__ bk,
    const float* __restrict__ Wv, const float* __restrict__ bv,
    unsigned short* __restrict__ qb, unsigned short* __restrict__ kb,
    unsigned short* __restrict__ vt)
{
  const int which = blockIdx.y;
  const float* __restrict__ src  = (which == 0) ? x  : cond;
  const float* __restrict__ W    = (which == 0) ? Wq : (which == 1 ? Wk : Wv);
  const float* __restrict__ bias = (which == 0) ? bq : (which == 1 ? bk : bv);
  const int r0 = blockIdx.x * 64;

  __shared__ __align__(16) char lds[32768];
  char* const AhB = lds;
  char* const AlB = lds + 8192;
  char* const WtB = lds + 16384;

  const int tid  = threadIdx.x;
  const int wv   = tid >> 6;
  const int lane = tid & 63;
  const int g    = lane >> 4;
  const int c    = lane & 15;

  f32x4 acc[8];
  #pragma unroll
  for (int cf = 0; cf < 8; ++cf) acc[cf] = (f32x4){0.f, 0.f, 0.f, 0.f};

  for (int kt = 0; kt < 4; ++kt) {
    #pragma unroll
    for (int i = 0; i < 4; ++i) {
      const int idx = tid + i * 256;
      const int row = idx >> 4, f4 = idx & 15;
      const float4 a4 =
          *(const float4*)(src + (size_t)(r0 + row) * DIN + kt * 64 + f4 * 4);
      us4 hi, lo;
      const float av[4] = {a4.x, a4.y, a4.z, a4.w};
      #pragma unroll
      for (int e = 0; e < 4; ++e) {
        hi[e] = bf16_rn(av[e]);
        lo[e] = bf16_rn(av[e] - bf16_f32(hi[e]));
      }
      const int off = swz128(row * 128 + f4 * 8);
      *(us4*)(AhB + off) = hi;
      *(us4*)(AlB + off) = lo;
    }
    {
      const int col = tid & 127, half = tid >> 7;
      #pragma unroll
      for (int j = 0; j < 4; ++j) {
        const int k0 = half * 32 + j * 8;
        ushort8 wb;
        #pragma unroll
        for (int e = 0; e < 8; ++e)
          wb[e] = bf16_rn(W[(size_t)(kt * 64 + k0 + e) * DOUT + col]);
        *(ushort8*)(WtB + swz128(col * 128 + k0 * 2)) = wb;
      }
    }
    __syncthreads();

    #pragma unroll
    for (int ks = 0; ks < 2; ++ks) {
      const int aoff = (wv * 16 + c) * 128 + ks * 64 + g * 16;
      const short8 ah = *(const short8*)(AhB + swz128(aoff));
      const short8 al = *(const short8*)(AlB + swz128(aoff));
      #pragma unroll
      for (int cf = 0; cf < 8; ++cf) {
        const short8 wb =
            *(const short8*)(WtB + swz128((cf * 16 + c) * 128 + ks * 64 + g * 16));
        acc[cf] = mfma_bf16(ah, wb, acc[cf]);
        acc[cf] = mfma_bf16(al, wb, acc[cf]);
      }
    }
    __syncthreads();
  }

  if (which == 0) {
    // q scaled by log2(e) in f32 BEFORE the bf16 round (exp2-domain softmax)
    #pragma unroll
    for (int cf = 0; cf < 8; ++cf) {
      const float bb = bias[cf * 16 + c];
      #pragma unroll
      for (int r = 0; r < 4; ++r)
        qb[(size_t)(r0 + wv * 16 + g * 4 + r) * DOUT + cf * 16 + c] =
            bf16_rn((acc[cf][r] + bb) * LOG2E);
    }
  } else if (which == 1) {
    // K: bounce through swizzled LDS tile, then coalesced fragment-major stores
    char* const Ktile = lds;   // 16KB
    #pragma unroll
    for (int cf = 0; cf < 8; ++cf) {
      const float bb = bias[cf * 16 + c];
      #pragma unroll
      for (int r = 0; r < 4; ++r) {
        const int row = wv * 16 + g * 4 + r;
        *(unsigned short*)(Ktile + swzK(row * 256 + (cf * 16 + c) * 2)) =
            bf16_rn(acc[cf][r] + bb);
      }
    }
    __syncthreads();
    const int b2     = r0 >> 12;
    const int kblkG0 = (r0 & 4095) >> 5;
    #pragma unroll
    for (int j = 0; j < 4; ++j) {
      const int i    = tid + j * 256;
      const int kblk = i >> 9;
      const int rem  = i & 511;
      const int f    = rem >> 6;
      const int ln   = rem & 63;
      const int row  = kblk * 32 + (ln & 31);
      const int colb = f * 32 + (ln >> 5) * 16;
      const ushort8 v = *(const ushort8*)(Ktile + swzK(row * 256 + colb));
      *(ushort8*)((char*)kb +
          (((size_t)(b2 * 128 + kblkG0 + kblk) * 8 + f) * 64 + ln) * 16) = v;
    }
  } else {
    // fragment-major V (4 consecutive keys -> one us4 store)
    const int keybase = r0 + wv * 16 + g * 4;
    const int b2   = keybase >> 12;
    const int kblk = (keybase & 4095) >> 5;
    const int kk   = (keybase >> 4) & 1;
    const int h    = (keybase >> 3) & 1;
    const int e0   = keybase & 7;
    #pragma unroll
    for (int cf = 0; cf < 8; ++cf) {
      const float bb = bias[cf * 16 + c];
      const int col  = cf * 16 + c;
      const int dblk = col >> 5, l31 = col & 31;
      us4 pk;
      #pragma unroll
      for (int r = 0; r < 4; ++r) pk[r] = bf16_rn(acc[cf][r] + bb);
      *(us4*)(vt + (((((size_t)b2 * 128 + kblk) * 4 + dblk) * 2 + kk) * 64 +
                    h * 32 + l31) * 8 + e0) = pk;
    }
  }
}

// ---------------- flash attention: async-LDS staged, q-shared tiles -------
// Block: 512 thr = 8 waves = 2 qsub x 4 splits; grid 256 = 1 block/CU.
// Per split: K/V double-buffered LDS tiles (32KB), shared by both qsub waves.
// qsub0 wave issues K gload_lds, qsub1 issues V (8 x 1KB each). Counted
// vmcnt(8) -> loads stay in flight across barriers (T4). Compute core = r10.
constexpr int NSPLIT = 4;
constexpr int KVBLK  = 32;
constexpr int ITERS  = SEQLEN / NSPLIT / KVBLK;   // 32

__global__ __launch_bounds__(512) void attn_kernel(
    const unsigned short* __restrict__ qb,
    const unsigned short* __restrict__ kb,
    const unsigned short* __restrict__ vt,
    float* __restrict__ out)
{
  // 128KB: per split s: K bufs at s*32768 + cur*8192, V at +16384 + cur*8192.
  // Epilogue reuses: Ml at [0], cmb regions at +8192.
  __shared__ __align__(16) char smem[131072];

  // XCD swizzle (256 blocks = 8 XCD x 32): one batch per XCD-pair -> L2-fit
  const int bid = ((blockIdx.x & 7) << 5) | (blockIdx.x >> 3);
  const int qt  = bid & 63;    // 64 q-tiles of 64 queries per batch
  const int b   = bid >> 6;
  const int tid   = threadIdx.x;
  const int wid   = tid >> 6;
  const int qsub  = wid & 1;
  const int split = wid >> 1;   // 0..3
  const int lane  = tid & 63;
  const int ql = lane & 31;     // query column this lane owns
  const int h  = lane >> 5;     // half-wave

  const int q0 = qt * 64 + qsub * 32;

  char* const KtB = smem + split * 32768;
  char* const VtB = smem + split * 32768 + 16384;

  // ---- Q B-fragments (once) ----
  short8 qf[8];
  {
    const char* qp = (const char*)(qb + (size_t)(b * SEQLEN + q0 + ql) * DOUT) + h * 16;
    #pragma unroll
    for (int f = 0; f < 8; ++f) qf[f] = *(const short8*)(qp + f * 32);
  }

  // ---- fragment-major global bases (per-lane) ----
  const int kblk0 = split * 32;
  const char* const kg = (const char*)kb + ((size_t)b * 128 + kblk0) * 8192 + lane * 16;
  const char* const vg = (const char*)vt + ((size_t)b * 128 + kblk0) * 8192 + lane * 16;

  f32x16 acc[4];
  #pragma unroll
  for (int d = 0; d < 4; ++d)
    #pragma unroll
    for (int r = 0; r < 16; ++r) acc[d][r] = 0.f;
  float mc = -1e30f, lc = 0.f;

  // ---- prologue: stage tile 0 into buf0 ----
  if (qsub == 0) {
    #pragma unroll
    for (int f = 0; f < 8; ++f) gl16(kg + f * 1024, KtB + f * 1024);
  } else {
    #pragma unroll
    for (int f = 0; f < 8; ++f) gl16(vg + f * 1024, VtB + f * 1024);
  }
  asm volatile("s_waitcnt vmcnt(0)" ::: "memory");
  __builtin_amdgcn_sched_barrier(0);
  __builtin_amdgcn_s_barrier();
  __builtin_amdgcn_sched_barrier(0);

  for (int t = 0; t < ITERS; ++t) {
    const int cur = t & 1;

    // ---- issue tile t+1 into the other buffer (counted vmcnt, T4) ----
    if (t + 1 < ITERS) {
      const int nxt = cur ^ 1;
      if (qsub == 0) {
        const char* g = kg + (size_t)(t + 1) * 8192;
        char* l = KtB + nxt * 8192;
        #pragma unroll
        for (int f = 0; f < 8; ++f) gl16(g + f * 1024, l + f * 1024);
      } else {
        const char* g = vg + (size_t)(t + 1) * 8192;
        char* l = VtB + nxt * 8192;
        #pragma unroll
        for (int f = 0; f < 8; ++f) gl16(g + f * 1024, l + f * 1024);
      }
      asm volatile("s_waitcnt vmcnt(8)" ::: "memory");  // t's loads retired
    } else {
      asm volatile("s_waitcnt vmcnt(0)" ::: "memory");
    }
    __builtin_amdgcn_sched_barrier(0);
    __builtin_amdgcn_s_barrier();          // partner's half of tile t ready
    __builtin_amdgcn_sched_barrier(0);

    const char* Kt = KtB + cur * 8192;
    const char* Vt = VtB + cur * 8192;

    // ---- S^T = K Q^T, two independent chains ----
    short8 kf[8];
    #pragma unroll
    for (int f = 0; f < 8; ++f)
      kf[f] = *(const short8*)(Kt + f * 1024 + lane * 16);
    f32x16 s0, s1;
    #pragma unroll
    for (int r = 0; r < 16; ++r) { s0[r] = 0.f; s1[r] = 0.f; }
    __builtin_amdgcn_s_setprio(1);
    #pragma unroll
    for (int f = 0; f < 4; ++f) s0 = mfma32(kf[f], qf[f], s0);
    #pragma unroll
    for (int f = 0; f < 4; ++f) s1 = mfma32(kf[f + 4], qf[f + 4], s1);
    __builtin_amdgcn_s_setprio(0);

    float s[16];
    #pragma unroll
    for (int r = 0; r < 16; ++r) s[r] = s0[r] + s1[r];

    // ---- softmax, defer-max (THR=11 log2 units: P <= 2048) ----
    float m01 = fmaxf(fmaxf(s[0],  s[1]),  s[2]);
    float m02 = fmaxf(fmaxf(s[3],  s[4]),  s[5]);
    float m03 = fmaxf(fmaxf(s[6],  s[7]),  s[8]);
    float m04 = fmaxf(fmaxf(s[9],  s[10]), s[11]);
    float m05 = fmaxf(fmaxf(s[12], s[13]), s[14]);
    float m11 = fmaxf(fmaxf(m01, m02), m03);
    float m12 = fmaxf(fmaxf(m04, m05), s[15]);
    float tm  = fmaxf(m11, m12);
    if (!__all(tm <= mc + 11.f)) {
      float tr = fmaxf(tm, __shfl_xor(tm, 32));
      const float mnew  = fmaxf(mc, tr);
      const float sc    = exp2n(mc - mnew);
      mc = mnew;
      lc *= sc;
      #pragma unroll
      for (int d = 0; d < 4; ++d)
        #pragma unroll
        for (int r = 0; r < 16; ++r) acc[d][r] *= sc;
    }
    float p[16];
    #pragma unroll
    for (int r = 0; r < 16; ++r) p[r] = exp2n(s[r] - mc);
    float a0 = (p[0]+p[1]) + (p[2]+p[3]);
    float a1 = (p[4]+p[5]) + (p[6]+p[7]);
    float a2 = (p[8]+p[9]) + (p[10]+p[11]);
    float a3 = (p[12]+p[13]) + (p[14]+p[15]);
    lc += (a0 + a1) + (a2 + a3);

    // ---- P -> B-fragments in-register (T12) ----
    short8 pfrag[2];
    #pragma unroll
    for (int kk = 0; kk < 2; ++kk) {
      unsigned int A  = cvt_pk(p[kk * 8 + 0], p[kk * 8 + 1]);
      unsigned int Bv = cvt_pk(p[kk * 8 + 2], p[kk * 8 + 3]);
      unsigned int C  = cvt_pk(p[kk * 8 + 4], p[kk * 8 + 5]);
      unsigned int Dv = cvt_pk(p[kk * 8 + 6], p[kk * 8 + 7]);
      permswap(A, C);
      permswap(Bv, Dv);
      const u32x4 w = {A, Bv, C, Dv};
      pfrag[kk] = __builtin_bit_cast(short8, w);
    }

    // ---- O^T += V^T P^T ----
    __builtin_amdgcn_s_setprio(1);
    #pragma unroll
    for (int d = 0; d < 4; ++d)
      #pragma unroll
      for (int kk = 0; kk < 2; ++kk) {
        const short8 vf = *(const short8*)(Vt + (d * 2 + kk) * 1024 + lane * 16);
        acc[d] = mfma32(vf, pfrag[kk], acc[d]);
      }
    __builtin_amdgcn_s_setprio(0);

    __builtin_amdgcn_sched_barrier(0);
    __builtin_amdgcn_s_barrier();          // all waves done reading buf cur
    __builtin_amdgcn_sched_barrier(0);
  }

  // ---- cross-split combine (exp2 domain), smem repurposed ----
  __syncthreads();
  float (*Ml)[NSPLIT][32][2] = (float(*)[NSPLIT][32][2])smem;   // [2][4][32][2]
  float* const cmbBase = (float*)(smem + 8192);  // 4 regions x 32x132 f32

  lc += __shfl_xor(lc, 32);
  if (lane < 32) { Ml[qsub][split][ql][0] = mc; Ml[qsub][split][ql][1] = lc; }
  __syncthreads();

  float mg = -1e30f, lsum = 0.f;
  #pragma unroll
  for (int s2 = 0; s2 < NSPLIT; ++s2) mg = fmaxf(mg, Ml[qsub][s2][ql][0]);
  #pragma unroll
  for (int s2 = 0; s2 < NSPLIT; ++s2)
    lsum += Ml[qsub][s2][ql][1] * exp2n(Ml[qsub][s2][ql][0] - mg);
  const float fac = exp2n(mc - mg);
  #pragma unroll
  for (int d = 0; d < 4; ++d)
    #pragma unroll
    for (int r = 0; r < 16; ++r) acc[d][r] *= fac;

  float* const reg0 = cmbBase + (qsub * 2 + 0) * (32 * 132);
  float* const reg1 = cmbBase + (qsub * 2 + 1) * (32 * 132);

  auto writeReg = [&](float* reg) {
    #pragma unroll
    for (int d = 0; d < 4; ++d)
      #pragma unroll
      for (int rr = 0; rr < 4; ++rr) {
        const f32x4 v = {acc[d][rr*4+0], acc[d][rr*4+1], acc[d][rr*4+2], acc[d][rr*4+3]};
        *(f32x4*)(reg + ql * 132 + d * 32 + rr * 8 + h * 4) = v;
      }
  };
  auto addReg = [&](const float* reg) {
    #pragma unroll
    for (int d = 0; d < 4; ++d)
      #pragma unroll
      for (int rr = 0; rr < 4; ++rr) {
        const f32x4 v = *(const f32x4*)(reg + ql * 132 + d * 32 + rr * 8 + h * 4);
        acc[d][rr*4+0] += v.x; acc[d][rr*4+1] += v.y;
        acc[d][rr*4+2] += v.z; acc[d][rr*4+3] += v.w;
      }
  };

  // tree per qsub: {1,3} write -> {0,2} add -> {2} writes -> {0} adds -> out
  if (split & 1) writeReg((split >> 1) ? reg1 : reg0);
  __syncthreads();
  if (!(split & 1)) addReg((split >> 1) ? reg1 : reg0);
  __syncthreads();
  if (split == 2) writeReg(reg0);
  __syncthreads();
  if (split == 0) {
    addReg(reg0);
    const float inv = 1.f / lsum;
    float* const op = out + (size_t)(b * SEQLEN + q0 + ql) * DOUT;
    #pragma unroll
    for (int d = 0; d < 4; ++d)
      #pragma unroll
      for (int rr = 0; rr < 4; ++rr) {
        f32x4 o;
        o.x = acc[d][rr*4+0] * inv;
        o.y = acc[d][rr*4+1] * inv;
        o.z = acc[d][rr*4+2] * inv;
        o.w = acc[d][rr*4+3] * inv;
        *(f32x4*)(op + d * 32 + rr * 8 + h * 4) = o;
      }
  }
}

extern "C" void kernel_launch(void* const* d_in, const int* in_sizes, int n_in,
                              void* d_out, int out_size, void* d_ws, size_t ws_size,
                              hipStream_t stream) {
  const float* x    = (const float*)d_in[0];
  const float* cond = (const float*)d_in[1];
  const float* Wq   = (const float*)d_in[2];
  const float* bq   = (const float*)d_in[3];
  const float* Wk   = (const float*)d_in[4];
  const float* bk   = (const float*)d_in[5];
  const float* Wv   = (const float*)d_in[6];
  const float* bv   = (const float*)d_in[7];
  float* out = (float*)d_out;

  unsigned short* qb = (unsigned short*)d_ws;                 // 4MB (log2e-scaled)
  unsigned short* kb = qb + (size_t)ROWS * DOUT;              // 4MB fragment-major
  unsigned short* vt = kb + (size_t)ROWS * DOUT;              // 4MB fragment-major

  proj_kernel<<<dim3(ROWS / 64, 3), 256, 0, stream>>>(
      x, cond, Wq, bq, Wk, bk, Wv, bv, qb, kb, vt);

  attn_kernel<<<dim3(BATCH * (SEQLEN / 64)), 512, 0, stream>>>(
      qb, kb, vt, out);
}